// Round 1
// baseline (1051.499 us; speedup 1.0000x reference)
//
#include <hip/hip_runtime.h>
#include <hip/hip_bf16.h>

#define BB 32
#define CC 64
#define HH 128
#define WW 128
#define OO 64
#define KK 4
#define HIDDEN 17
#define HW (HH*WW)

// ---------------- Kernel 1: adaptive avg pool to [B,C] ----------------
__global__ __launch_bounds__(256) void pool_kernel(const float* __restrict__ x,
                                                   float* __restrict__ pooled) {
    int bc = blockIdx.x;              // 0..2047  (b*64 + c)
    const float* p = x + (size_t)bc * HW;
    float s = 0.f;
    for (int i = threadIdx.x; i < HW; i += 256) s += p[i];
    // wave64 reduce
    #pragma unroll
    for (int off = 32; off > 0; off >>= 1) s += __shfl_down(s, off, 64);
    __shared__ float warp_s[4];
    int lane = threadIdx.x & 63, wv = threadIdx.x >> 6;
    if (lane == 0) warp_s[wv] = s;
    __syncthreads();
    if (threadIdx.x == 0) {
        float t = warp_s[0] + warp_s[1] + warp_s[2] + warp_s[3];
        pooled[bc] = t * (1.f / (float)HW);
    }
}

// ---------------- Kernel 2: MLP -> softmax -> attn, agg_b ----------------
__global__ __launch_bounds__(256) void attn_kernel(const float* __restrict__ pooled,
                                                   const float* __restrict__ fc1_w,
                                                   const float* __restrict__ fc2_w,
                                                   const float* __restrict__ fc2_b,
                                                   const float* __restrict__ scale,
                                                   const float* __restrict__ bias,
                                                   float* __restrict__ attn,
                                                   float* __restrict__ agg_b) {
    __shared__ float s_attn[BB * KK];
    int tid = threadIdx.x;
    if (tid < BB) {
        int b = tid;
        const float* pb = pooled + b * CC;
        float h[HIDDEN];
        #pragma unroll
        for (int i = 0; i < HIDDEN; ++i) {
            float s = 0.f;
            for (int c = 0; c < CC; ++c) s += pb[c] * fc1_w[i * CC + c];
            h[i] = fmaxf(s, 0.f);
        }
        float sc = scale[0];
        float logits[KK];
        #pragma unroll
        for (int k = 0; k < KK; ++k) {
            float s = fc2_b[k];
            for (int j = 0; j < HIDDEN; ++j) s += h[j] * fc2_w[k * (HIDDEN + 2) + j];
            s += sc * fc2_w[k * (HIDDEN + 2) + HIDDEN];
            s += sc * fc2_w[k * (HIDDEN + 2) + HIDDEN + 1];
            logits[k] = s;
        }
        float m = fmaxf(fmaxf(logits[0], logits[1]), fmaxf(logits[2], logits[3]));
        float e[KK], tot = 0.f;
        #pragma unroll
        for (int k = 0; k < KK; ++k) { e[k] = __expf(logits[k] - m); tot += e[k]; }
        float inv = 1.f / tot;
        #pragma unroll
        for (int k = 0; k < KK; ++k) {
            float a = e[k] * inv;
            s_attn[b * KK + k] = a;
            attn[b * KK + k] = a;
        }
    }
    __syncthreads();
    for (int i = tid; i < BB * OO; i += blockDim.x) {
        int b = i >> 6;
        int o = i & 63;
        float s = 0.f;
        #pragma unroll
        for (int k = 0; k < KK; ++k) s += s_attn[b * KK + k] * bias[k * OO + o];
        agg_b[i] = s;
    }
}

// ---------------- Kernel 3: mix expert weights -> agg_w [b][c][o][3][3] ----------------
__global__ __launch_bounds__(256) void aggw_kernel(const float* __restrict__ attn,
                                                   const float* __restrict__ weight,
                                                   float* __restrict__ agg_w) {
    int idx = blockIdx.x * 256 + threadIdx.x;
    const int total = BB * CC * OO * 9;
    if (idx >= total) return;
    int j  = idx % 9;
    int t  = idx / 9;
    int o  = t & 63;
    int t2 = t >> 6;
    int c  = t2 & 63;
    int b  = t2 >> 6;
    float s = 0.f;
    #pragma unroll
    for (int k = 0; k < KK; ++k)
        s += attn[b * KK + k] * weight[((k * OO + o) * CC + c) * 9 + j];
    agg_w[idx] = s;   // layout [b][c][o][kh][kw]
}

// ---------------- Kernel 4: per-sample 3x3 conv ----------------
// grid: (64 spatial tiles, 8 o-tiles, 32 batches), block 256 = 16x16
__global__ __launch_bounds__(256) void conv_kernel(const float* __restrict__ x,
                                                   const float* __restrict__ agg_w,
                                                   const float* __restrict__ agg_b,
                                                   float* __restrict__ out) {
    __shared__ float s_in[2][18 * 18];
    const int tid = threadIdx.x;
    const int tx = tid & 15, ty = tid >> 4;
    const int b  = blockIdx.z;
    const int o0 = blockIdx.y * 8;
    const int sy = (blockIdx.x >> 3) * 16;
    const int sx = (blockIdx.x & 7) * 16;

    const float* __restrict__ xb = x + (size_t)b * CC * HW;
    const float* __restrict__ wb = agg_w + (size_t)b * CC * OO * 9;  // [c][o][9]

    float acc[8];
    #pragma unroll
    for (int o = 0; o < 8; ++o) acc[o] = agg_b[b * OO + o0 + o];

    // stage channel c's 18x18 halo tile into dst
    auto load_ch = [&](int c, float* dst) {
        for (int i = tid; i < 18 * 18; i += 256) {
            int r   = i / 18;
            int col = i - r * 18;
            int gy = sy + r - 1;
            int gx = sx + col - 1;
            float v = 0.f;
            if (gy >= 0 && gy < HH && gx >= 0 && gx < WW)
                v = xb[c * HW + gy * WW + gx];
            dst[i] = v;
        }
    };

    load_ch(0, s_in[0]);
    __syncthreads();

    for (int c = 0; c < CC; ++c) {
        const int buf = c & 1;
        if (c + 1 < CC) load_ch(c + 1, s_in[buf ^ 1]);

        float in[3][3];
        #pragma unroll
        for (int kh = 0; kh < 3; ++kh)
            #pragma unroll
            for (int kw = 0; kw < 3; ++kw)
                in[kh][kw] = s_in[buf][(ty + kh) * 18 + (tx + kw)];

        // 72 contiguous, block-uniform weights -> scalar loads / SGPRs
        const float* __restrict__ wc = wb + (c * OO + o0) * 9;
        #pragma unroll
        for (int o = 0; o < 8; ++o) {
            #pragma unroll
            for (int kh = 0; kh < 3; ++kh)
                #pragma unroll
                for (int kw = 0; kw < 3; ++kw)
                    acc[o] += in[kh][kw] * wc[o * 9 + kh * 3 + kw];
        }
        __syncthreads();
    }

    const int oy = sy + ty, ox = sx + tx;
    #pragma unroll
    for (int o = 0; o < 8; ++o)
        out[((size_t)(b * OO + o0 + o) * HH + oy) * WW + ox] = acc[o];
}

extern "C" void kernel_launch(void* const* d_in, const int* in_sizes, int n_in,
                              void* d_out, int out_size, void* d_ws, size_t ws_size,
                              hipStream_t stream) {
    const float* x      = (const float*)d_in[0];
    const float* scale  = (const float*)d_in[1];
    const float* fc1_w  = (const float*)d_in[2];
    const float* fc2_w  = (const float*)d_in[3];
    const float* fc2_b  = (const float*)d_in[4];
    const float* weight = (const float*)d_in[5];
    const float* bias   = (const float*)d_in[6];
    float* out = (float*)d_out;

    float* ws      = (float*)d_ws;
    float* attn    = ws;                    // 32*4
    float* agg_b   = ws + 128;              // 32*64
    float* pooled  = ws + 128 + 2048;       // 32*64
    float* agg_w   = ws + 128 + 2048 + 2048; // 32*64*64*9 = 1,179,648

    pool_kernel<<<BB * CC, 256, 0, stream>>>(x, pooled);
    attn_kernel<<<1, 256, 0, stream>>>(pooled, fc1_w, fc2_w, fc2_b, scale, bias, attn, agg_b);
    const int aggw_total = BB * CC * OO * 9;
    aggw_kernel<<<(aggw_total + 255) / 256, 256, 0, stream>>>(attn, weight, agg_w);
    conv_kernel<<<dim3(64, 8, BB), 256, 0, stream>>>(x, agg_w, agg_b, out);
}

// Round 2
// 512.364 us; speedup vs baseline: 2.0522x; 2.0522x over previous
//
#include <hip/hip_runtime.h>
#include <hip/hip_bf16.h>

#define BB 32
#define CC 64
#define HH 128
#define WW 128
#define OO 64
#define KK 4
#define HIDDEN 17
#define HW (HH*WW)

typedef __attribute__((ext_vector_type(8)))  short bf16x8;
typedef __attribute__((ext_vector_type(16))) float f32x16;

__device__ __forceinline__ unsigned short f2bf(float f) {
    unsigned u = __float_as_uint(f);
    unsigned r = (u + 0x7FFFu + ((u >> 16) & 1u)) >> 16;   // RNE
    return (unsigned short)r;
}

// ---------------- Kernel 1: adaptive avg pool to [B,C] ----------------
__global__ __launch_bounds__(256) void pool_kernel(const float* __restrict__ x,
                                                   float* __restrict__ pooled) {
    int bc = blockIdx.x;              // b*64 + c
    const float* p = x + (size_t)bc * HW;
    float s = 0.f;
    for (int i = threadIdx.x; i < HW; i += 256) s += p[i];
    #pragma unroll
    for (int off = 32; off > 0; off >>= 1) s += __shfl_down(s, off, 64);
    __shared__ float warp_s[4];
    int lane = threadIdx.x & 63, wv = threadIdx.x >> 6;
    if (lane == 0) warp_s[wv] = s;
    __syncthreads();
    if (threadIdx.x == 0) {
        float t = warp_s[0] + warp_s[1] + warp_s[2] + warp_s[3];
        pooled[bc] = t * (1.f / (float)HW);
    }
}

// ---------------- Kernel 2: MLP -> softmax -> attn, agg_b ----------------
__global__ __launch_bounds__(256) void attn_kernel(const float* __restrict__ pooled,
                                                   const float* __restrict__ fc1_w,
                                                   const float* __restrict__ fc2_w,
                                                   const float* __restrict__ fc2_b,
                                                   const float* __restrict__ scale,
                                                   const float* __restrict__ bias,
                                                   float* __restrict__ attn,
                                                   float* __restrict__ agg_b) {
    __shared__ float s_attn[BB * KK];
    int tid = threadIdx.x;
    if (tid < BB) {
        int b = tid;
        const float* pb = pooled + b * CC;
        float h[HIDDEN];
        #pragma unroll
        for (int i = 0; i < HIDDEN; ++i) {
            float s = 0.f;
            for (int c = 0; c < CC; ++c) s += pb[c] * fc1_w[i * CC + c];
            h[i] = fmaxf(s, 0.f);
        }
        float sc = scale[0];
        float logits[KK];
        #pragma unroll
        for (int k = 0; k < KK; ++k) {
            float s = fc2_b[k];
            for (int j = 0; j < HIDDEN; ++j) s += h[j] * fc2_w[k * (HIDDEN + 2) + j];
            s += sc * fc2_w[k * (HIDDEN + 2) + HIDDEN];
            s += sc * fc2_w[k * (HIDDEN + 2) + HIDDEN + 1];
            logits[k] = s;
        }
        float m = fmaxf(fmaxf(logits[0], logits[1]), fmaxf(logits[2], logits[3]));
        float e[KK], tot = 0.f;
        #pragma unroll
        for (int k = 0; k < KK; ++k) { e[k] = __expf(logits[k] - m); tot += e[k]; }
        float inv = 1.f / tot;
        #pragma unroll
        for (int k = 0; k < KK; ++k) {
            float a = e[k] * inv;
            s_attn[b * KK + k] = a;
            attn[b * KK + k] = a;
        }
    }
    __syncthreads();
    for (int i = tid; i < BB * OO; i += blockDim.x) {
        int b = i >> 6;
        int o = i & 63;
        float s = 0.f;
        #pragma unroll
        for (int k = 0; k < KK; ++k) s += s_attn[b * KK + k] * bias[k * OO + o];
        agg_b[i] = s;
    }
}

// ---------------- Kernel 3a (MFMA path): mix weights -> bf16 [b][j9][o][c] ----------------
__global__ __launch_bounds__(256) void aggw_bf_kernel(const float* __restrict__ attn,
                                                      const float* __restrict__ weight,
                                                      unsigned int* __restrict__ wbf) {
    // one thread per (b, j9, o, c-pair); packs 2 bf16 into u32
    int idx = blockIdx.x * 256 + threadIdx.x;
    const int total = BB * 9 * OO * (CC / 2);
    if (idx >= total) return;
    int cp = idx & 31;          // c pair
    int t  = idx >> 5;
    int o  = t & 63;
    int t2 = t >> 6;
    int j  = t2 % 9;
    int b  = t2 / 9;
    float a0 = attn[b * KK + 0], a1 = attn[b * KK + 1],
          a2 = attn[b * KK + 2], a3 = attn[b * KK + 3];
    int c0 = cp * 2;
    float s0 = 0.f, s1 = 0.f;
    s0 += a0 * weight[((0 * OO + o) * CC + c0) * 9 + j];
    s1 += a0 * weight[((0 * OO + o) * CC + c0 + 1) * 9 + j];
    s0 += a1 * weight[((1 * OO + o) * CC + c0) * 9 + j];
    s1 += a1 * weight[((1 * OO + o) * CC + c0 + 1) * 9 + j];
    s0 += a2 * weight[((2 * OO + o) * CC + c0) * 9 + j];
    s1 += a2 * weight[((2 * OO + o) * CC + c0 + 1) * 9 + j];
    s0 += a3 * weight[((3 * OO + o) * CC + c0) * 9 + j];
    s1 += a3 * weight[((3 * OO + o) * CC + c0 + 1) * 9 + j];
    unsigned int pack = (unsigned int)f2bf(s0) | ((unsigned int)f2bf(s1) << 16);
    wbf[idx] = pack;            // layout [b][j][o][c] (c contiguous)
}

// ---------------- Kernel 3b: zero padded borders of x_bf ----------------
// x_bf layout: [b][yp 0..129][xp 0..129][c 0..63] bf16
__global__ __launch_bounds__(256) void border_kernel(unsigned int* __restrict__ xbf32) {
    int yp = blockIdx.x;        // 0..129
    int b  = blockIdx.y;
    unsigned int* row = xbf32 + ((size_t)b * 130 + yp) * 130 * 32;  // u32 units
    if (yp == 0 || yp == 129) {
        for (int i = threadIdx.x; i < 130 * 32; i += 256) row[i] = 0u;
    } else {
        if (threadIdx.x < 32) row[threadIdx.x] = 0u;                       // xp = 0
        else if (threadIdx.x >= 64 && threadIdx.x < 96)
            row[129 * 32 + (threadIdx.x - 64)] = 0u;                       // xp = 129
    }
}

// ---------------- Kernel 3c: transpose x NCHW fp32 -> padded [b][yp][xp][c] bf16 ----------------
__global__ __launch_bounds__(256) void xpose_kernel(const float* __restrict__ x,
                                                    unsigned int* __restrict__ xbf32) {
    __shared__ float t[64][65];
    const int y  = blockIdx.x;          // 0..127
    const int b  = blockIdx.y;          // 0..31
    const int x0 = blockIdx.z * 64;     // 0 or 64
    const int tid = threadIdx.x;
    // load: 64 c x 64 x, coalesced along x
    {
        const int xl = tid & 63;
        const int cs = tid >> 6;        // 0..3
        #pragma unroll
        for (int cc = 0; cc < 16; ++cc) {
            int c = cc * 4 + cs;
            t[c][xl] = x[((size_t)(b * CC + c) * HH + y) * WW + x0 + xl];
        }
    }
    __syncthreads();
    // store: pack 2 c's per u32, coalesced along c
    {
        const int cp = tid & 31;        // c pair 0..31
        const int xs = tid >> 5;        // 0..7
        const int c0 = cp * 2;
        #pragma unroll
        for (int xx = 0; xx < 8; ++xx) {
            int xl = xx * 8 + xs;
            unsigned int pack = (unsigned int)f2bf(t[c0][xl]) |
                                ((unsigned int)f2bf(t[c0 + 1][xl]) << 16);
            xbf32[(((size_t)b * 130 + (y + 1)) * 130 + (x0 + xl + 1)) * 32 + cp] = pack;
        }
    }
}

// ---------------- Kernel 4 (MFMA path): per-sample conv as implicit GEMM ----------------
// grid (y=128, b=32), block 256 = 4 waves.
// wave w: o-tile o0 = (w&1)*32 ; x-tile x0 = (w>>1)*64, covering two 32-wide n sub-tiles.
// No LDS, no barriers: A/B fragments straight from global (L1/L2-resident).
__global__ __launch_bounds__(256) void conv_mfma_kernel(const short* __restrict__ xbf,
                                                        const short* __restrict__ wbf,
                                                        const float* __restrict__ agg_b,
                                                        float* __restrict__ out) {
    const int y    = blockIdx.x;
    const int b    = blockIdx.y;
    const int tid  = threadIdx.x;
    const int lane = tid & 63;
    const int w    = tid >> 6;
    const int o0   = (w & 1) * 32;
    const int x0   = (w >> 1) * 64;
    const int m    = lane & 31;     // A: o offset; B: n offset; C/D: col
    const int kh2  = lane >> 5;     // k-half

    f32x16 acc0 = {0,0,0,0,0,0,0,0,0,0,0,0,0,0,0,0};
    f32x16 acc1 = {0,0,0,0,0,0,0,0,0,0,0,0,0,0,0,0};

    // A[m][k]: k = kh2*8 + j, element = w[o0+m][c = c0 + kh2*8 + j] for expert-tap j9
    const short* Abase = wbf + (((size_t)b * 9) * OO + (o0 + m)) * CC + kh2 * 8;
    // B[k][n]: n = m, element = xbf[b][y+kh][x0+n+kw][c0 + kh2*8 + j]
    const short* Bbase = xbf + (((size_t)b * 130 + y) * 130 + (x0 + m)) * CC + kh2 * 8;

    #pragma unroll
    for (int j9 = 0; j9 < 9; ++j9) {
        const int kh = j9 / 3, kw = j9 % 3;
        const short* Aj = Abase + j9 * (OO * CC);
        const short* Bj = Bbase + (kh * 130 + kw) * CC;
        #pragma unroll
        for (int kc = 0; kc < 4; ++kc) {
            bf16x8 a  = *(const bf16x8*)(Aj + kc * 16);
            bf16x8 b0 = *(const bf16x8*)(Bj + kc * 16);
            bf16x8 b1 = *(const bf16x8*)(Bj + 32 * CC + kc * 16);
            acc0 = __builtin_amdgcn_mfma_f32_32x32x16_bf16(a, b0, acc0, 0, 0, 0);
            acc1 = __builtin_amdgcn_mfma_f32_32x32x16_bf16(a, b1, acc1, 0, 0, 0);
        }
    }

    // epilogue: C/D row = (r&3) + 8*(r>>2) + 4*kh2 ; col = m
    #pragma unroll
    for (int r = 0; r < 16; ++r) {
        int o = o0 + (r & 3) + 8 * (r >> 2) + 4 * kh2;
        float bias = agg_b[b * OO + o];
        size_t base = ((size_t)(b * OO + o) * HH + y) * WW;
        out[base + x0 + m]      = acc0[r] + bias;
        out[base + x0 + 32 + m] = acc1[r] + bias;
    }
}

// ================= fallback fp32 path (if workspace too small) =================
__global__ __launch_bounds__(256) void aggw_kernel(const float* __restrict__ attn,
                                                   const float* __restrict__ weight,
                                                   float* __restrict__ agg_w) {
    int idx = blockIdx.x * 256 + threadIdx.x;
    const int total = BB * CC * OO * 9;
    if (idx >= total) return;
    int j  = idx % 9;
    int t  = idx / 9;
    int o  = t & 63;
    int t2 = t >> 6;
    int c  = t2 & 63;
    int b  = t2 >> 6;
    float s = 0.f;
    #pragma unroll
    for (int k = 0; k < KK; ++k)
        s += attn[b * KK + k] * weight[((k * OO + o) * CC + c) * 9 + j];
    agg_w[idx] = s;
}

__global__ __launch_bounds__(256) void conv_kernel(const float* __restrict__ x,
                                                   const float* __restrict__ agg_w,
                                                   const float* __restrict__ agg_b,
                                                   float* __restrict__ out) {
    __shared__ float s_in[2][18 * 20];   // stride 20: kill bank conflicts
    const int tid = threadIdx.x;
    const int tx = tid & 15, ty = tid >> 4;
    const int b  = blockIdx.z;
    const int o0 = blockIdx.y * 8;
    const int sy = (blockIdx.x >> 3) * 16;
    const int sx = (blockIdx.x & 7) * 16;

    const float* __restrict__ xb = x + (size_t)b * CC * HW;
    const float* __restrict__ wb = agg_w + (size_t)b * CC * OO * 9;

    float acc[8];
    #pragma unroll
    for (int o = 0; o < 8; ++o) acc[o] = agg_b[b * OO + o0 + o];

    auto load_ch = [&](int c, float* dst) {
        for (int i = tid; i < 18 * 18; i += 256) {
            int r   = i / 18;
            int col = i - r * 18;
            int gy = sy + r - 1;
            int gx = sx + col - 1;
            float v = 0.f;
            if (gy >= 0 && gy < HH && gx >= 0 && gx < WW)
                v = xb[c * HW + gy * WW + gx];
            dst[r * 20 + col] = v;
        }
    };

    load_ch(0, s_in[0]);
    __syncthreads();

    for (int c = 0; c < CC; ++c) {
        const int buf = c & 1;
        if (c + 1 < CC) load_ch(c + 1, s_in[buf ^ 1]);
        float in[3][3];
        #pragma unroll
        for (int kh = 0; kh < 3; ++kh)
            #pragma unroll
            for (int kw = 0; kw < 3; ++kw)
                in[kh][kw] = s_in[buf][(ty + kh) * 20 + (tx + kw)];
        const float* __restrict__ wc = wb + (c * OO + o0) * 9;
        #pragma unroll
        for (int o = 0; o < 8; ++o)
            #pragma unroll
            for (int kh = 0; kh < 3; ++kh)
                #pragma unroll
                for (int kw = 0; kw < 3; ++kw)
                    acc[o] += in[kh][kw] * wc[o * 9 + kh * 3 + kw];
        __syncthreads();
    }

    const int oy = sy + ty, ox = sx + tx;
    #pragma unroll
    for (int o = 0; o < 8; ++o)
        out[((size_t)(b * OO + o0 + o) * HH + oy) * WW + ox] = acc[o];
}

extern "C" void kernel_launch(void* const* d_in, const int* in_sizes, int n_in,
                              void* d_out, int out_size, void* d_ws, size_t ws_size,
                              hipStream_t stream) {
    const float* x      = (const float*)d_in[0];
    const float* scale  = (const float*)d_in[1];
    const float* fc1_w  = (const float*)d_in[2];
    const float* fc2_w  = (const float*)d_in[3];
    const float* fc2_b  = (const float*)d_in[4];
    const float* weight = (const float*)d_in[5];
    const float* bias   = (const float*)d_in[6];
    float* out = (float*)d_out;

    // workspace layout (MFMA path):
    //   xbf   : 32*130*130*64 bf16 = 69,222,400 B   (offset 0)
    //   wbf   : 32*9*64*64   bf16 =  2,359,296 B
    //   floats: pooled[2048] attn[128] agg_b[2048]
    const size_t XBF_BYTES = (size_t)BB * 130 * 130 * CC * 2;
    const size_t WBF_BYTES = (size_t)BB * 9 * OO * CC * 2;
    const size_t NEED = XBF_BYTES + WBF_BYTES + (2048 + 128 + 2048) * 4 + 256;

    if (ws_size >= NEED) {
        short*        xbf   = (short*)d_ws;
        unsigned int* xbf32 = (unsigned int*)d_ws;
        unsigned int* wbf32 = (unsigned int*)((char*)d_ws + XBF_BYTES);
        short*        wbf   = (short*)wbf32;
        float*        fls   = (float*)((char*)d_ws + XBF_BYTES + WBF_BYTES);
        float* pooled = fls;
        float* attn   = fls + 2048;
        float* agg_b  = fls + 2048 + 128;

        pool_kernel<<<BB * CC, 256, 0, stream>>>(x, pooled);
        attn_kernel<<<1, 256, 0, stream>>>(pooled, fc1_w, fc2_w, fc2_b, scale, bias, attn, agg_b);
        const int aggw_total = BB * 9 * OO * (CC / 2);
        aggw_bf_kernel<<<(aggw_total + 255) / 256, 256, 0, stream>>>(attn, weight, wbf32);
        border_kernel<<<dim3(130, BB), 256, 0, stream>>>(xbf32);
        xpose_kernel<<<dim3(HH, BB, 2), 256, 0, stream>>>(x, xbf32);
        conv_mfma_kernel<<<dim3(HH, BB), 256, 0, stream>>>(xbf, wbf, agg_b, out);
    } else {
        float* ws     = (float*)d_ws;
        float* attn   = ws;
        float* agg_b  = ws + 128;
        float* pooled = ws + 128 + 2048;
        float* agg_w  = ws + 128 + 2048 + 2048;
        pool_kernel<<<BB * CC, 256, 0, stream>>>(x, pooled);
        attn_kernel<<<1, 256, 0, stream>>>(pooled, fc1_w, fc2_w, fc2_b, scale, bias, attn, agg_b);
        const int aggw_total = BB * CC * OO * 9;
        aggw_kernel<<<(aggw_total + 255) / 256, 256, 0, stream>>>(attn, weight, agg_w);
        conv_kernel<<<dim3(64, 8, BB), 256, 0, stream>>>(x, agg_w, agg_b, out);
    }
}